// Round 17
// baseline (336.850 us; speedup 1.0000x reference)
//
#include <hip/hip_runtime.h>
#include <hip/hip_bf16.h>

#define DEV __device__ __forceinline__

typedef __bf16 bf16x8 __attribute__((ext_vector_type(8)));
typedef __bf16 bf16x2v __attribute__((ext_vector_type(2)));
typedef float f32x4 __attribute__((ext_vector_type(4)));
typedef float f32x16 __attribute__((ext_vector_type(16)));
typedef unsigned int u32;
typedef unsigned int u32x4 __attribute__((ext_vector_type(4)));
typedef __hip_bfloat16 hbf;

constexpr int Dm = 1024;
constexpr int Hh = 16;
constexpr int Ss = 2048;
constexpr int Bb = 4;
constexpr int DFm = 4096;
constexpr int LDQ = 3072;  // fused qkv row stride

DEV unsigned short f2bfu(float f) {
  hbf h = __float2bfloat16(f);
  return __builtin_bit_cast(unsigned short, h);
}

DEV float bfu2f(unsigned short u) { return __builtin_bit_cast(float, (u32)u << 16); }

DEV u32 pkbf(float x, float y) {
  bf16x2v v = {(__bf16)x, (__bf16)y};
  return __builtin_bit_cast(u32, v);
}

DEV float gelu_f(float x) {
  float e = __expf(-1.5957691216057308f * (x + 0.044715f * x * x * x));
  return x * __builtin_amdgcn_rcpf(1.f + e);
}

template <int N>
DEV void s_vmcnt() {
  if constexpr (N == 0) asm volatile("s_waitcnt vmcnt(0)" ::: "memory");
  else if constexpr (N == 5) asm volatile("s_waitcnt vmcnt(5)" ::: "memory");
  else if constexpr (N == 6) asm volatile("s_waitcnt vmcnt(6)" ::: "memory");
  else if constexpr (N == 8) asm volatile("s_waitcnt vmcnt(8)" ::: "memory");
  else static_assert(N == 0, "unsupported vmcnt");
}

#define GLDS(src, dst)                                                                     \
  __builtin_amdgcn_global_load_lds((const __attribute__((address_space(1))) void*)(src),   \
                                   (__attribute__((address_space(3))) void*)(dst), 16, 0, 0)

// ========== fused prep: 6 weight transposes (blocks 0..12287) + LN1 (blocks 12288..20479) =
__global__ __launch_bounds__(256) void prep_kernel(
    const float* __restrict__ Wq, const float* __restrict__ Wk,
    const float* __restrict__ Wv, const float* __restrict__ Wo,
    const float* __restrict__ W1, const float* __restrict__ W2,
    hbf* __restrict__ dqkv, hbf* __restrict__ dwo,
    hbf* __restrict__ dw1, hbf* __restrict__ dw2,
    const float* __restrict__ x, const float* __restrict__ g1,
    const float* __restrict__ s1, hbf* __restrict__ xln) {
  const int i = blockIdx.x;
  if (i < 12288) {
    __shared__ float tile[32][33];
    const float* W;
    hbf* Wt;
    int K, N, k0, n0;
    if (i < 4096) {
      int z = i >> 10, j = i & 1023;
      W = z == 0 ? Wq : z == 1 ? Wk : z == 2 ? Wv : Wo;
      Wt = z == 3 ? dwo : dqkv + (size_t)z * 1024 * 1024;
      K = 1024; N = 1024; k0 = (j & 31) * 32; n0 = (j >> 5) * 32;
    } else if (i < 8192) {
      int j = i - 4096;
      W = W1; Wt = dw1; K = 1024; N = 4096;
      k0 = (j & 31) * 32; n0 = (j >> 5) * 32;
    } else {
      int j = i - 8192;
      W = W2; Wt = dw2; K = 4096; N = 1024;
      k0 = (j & 127) * 32; n0 = (j >> 7) * 32;
    }
    int tx = threadIdx.x & 31, ty = threadIdx.x >> 5;
    for (int r = ty; r < 32; r += 8) tile[r][tx] = W[(size_t)(k0 + r) * N + n0 + tx];
    __syncthreads();
    for (int r = ty; r < 32; r += 8)
      Wt[(size_t)(n0 + r) * K + k0 + tx] = __float2bfloat16(tile[tx][r]);
  } else {
    const int bid = i - 12288;
    int row = ((bid & 7) << 10) | (bid >> 3);  // row->XCD remap
    int t = threadIdx.x;
    float4 v = ((const float4*)(x + (size_t)row * Dm))[t];
    float s = v.x + v.y + v.z + v.w;
    float q = v.x * v.x + v.y * v.y + v.z * v.z + v.w * v.w;
#pragma unroll
    for (int off = 32; off > 0; off >>= 1) {
      s += __shfl_down(s, off);
      q += __shfl_down(q, off);
    }
    __shared__ float red[10];
    int wave = t >> 6, lane = t & 63;
    if (lane == 0) { red[wave] = s; red[4 + wave] = q; }
    __syncthreads();
    if (t == 0) {
      float ts = red[0] + red[1] + red[2] + red[3];
      float tq = red[4] + red[5] + red[6] + red[7];
      float mean = ts * (1.f / Dm);
      float var = tq * (1.f / Dm) - mean * mean;
      red[8] = mean;
      red[9] = rsqrtf(var + 1e-5f);
    }
    __syncthreads();
    float mean = red[8], inv = red[9];
    float4 gv = ((const float4*)g1)[t];
    float4 bv = ((const float4*)s1)[t];
    ushort4 o;
    o.x = f2bfu(gv.x * (v.x - mean) * inv + bv.x);
    o.y = f2bfu(gv.y * (v.y - mean) * inv + bv.y);
    o.z = f2bfu(gv.z * (v.z - mean) * inv + bv.z);
    o.w = f2bfu(gv.w * (v.w - mean) * inv + bv.w);
    ((ushort4*)(xln + (size_t)row * Dm))[t] = o;
  }
}

// ---------------- layernorm (bf16 in, bf16 out), one block per row, row->XCD remap --------
__global__ __launch_bounds__(256) void ln_kernel(const hbf* __restrict__ xv,
                                                 const float* __restrict__ g,
                                                 const float* __restrict__ b,
                                                 hbf* __restrict__ y) {
  int row = ((blockIdx.x & 7) << 10) | (blockIdx.x >> 3);
  int t = threadIdx.x;
  float4 v;
  ushort4 u = ((const ushort4*)(xv + (size_t)row * Dm))[t];
  v.x = bfu2f(u.x); v.y = bfu2f(u.y); v.z = bfu2f(u.z); v.w = bfu2f(u.w);
  float s = v.x + v.y + v.z + v.w;
  float q = v.x * v.x + v.y * v.y + v.z * v.z + v.w * v.w;
#pragma unroll
  for (int off = 32; off > 0; off >>= 1) {
    s += __shfl_down(s, off);
    q += __shfl_down(q, off);
  }
  __shared__ float red[10];
  int wave = t >> 6, lane = t & 63;
  if (lane == 0) { red[wave] = s; red[4 + wave] = q; }
  __syncthreads();
  if (t == 0) {
    float ts = red[0] + red[1] + red[2] + red[3];
    float tq = red[4] + red[5] + red[6] + red[7];
    float mean = ts * (1.f / Dm);
    float var = tq * (1.f / Dm) - mean * mean;
    red[8] = mean;
    red[9] = rsqrtf(var + 1e-5f);
  }
  __syncthreads();
  float mean = red[8], inv = red[9];
  float4 gv = ((const float4*)g)[t];
  float4 bv = ((const float4*)b)[t];
  ushort4 o;
  o.x = f2bfu(gv.x * (v.x - mean) * inv + bv.x);
  o.y = f2bfu(gv.y * (v.y - mean) * inv + bv.y);
  o.z = f2bfu(gv.z * (v.z - mean) * inv + bv.z);
  o.w = f2bfu(gv.w * (v.w - mean) * inv + bv.w);
  ((ushort4*)(y + (size_t)row * Dm))[t] = o;
}

// ================= tiled GEMM, single-phase K-loop, 2 blocks/CU, L2-supertiled ============
// C[M,N] = A[M,K](bf16) @ Bt[N,K]^T(bf16). BK=64. NTHR=256 = 2x2 waves. BM=BN=128.
// LDS: 2 buffers x {A(2 slabs), B(2 slabs)} of (128/2) rows x 64 (contiguous 128B rows,
// full-cacheline gload_lds, source-chunk XOR swizzle c^(r&7), conflict-free reads).
// SINGLE-PHASE schedule (R17): per K-tile { read 16 frags(p); lgkmcnt(0); 32 MFMA;
// barrier [all reads of p done]; stage(t+2)->p (8 loads); vmcnt(8) [drain t+1, keep t+2];
// barrier }. 2 barriers/K-tile (was 4), counted-vmcnt pipeline depth 2 K-tiles.
// Block->tile order: bid = oidx*8 + xcd; oidx walks 8m x 8n supertile groups (L2-resident).
// VTR: QKV writes V panels (col>=2048) directly transposed to vtrout. RES: 0/1 fp32/2 bf16.
template <int BM, int BN, int WM, int WN, int NTHR, int ACT, bool HAS_BIAS, int RES,
          bool OUT_BF16, int VTR>
__global__ __launch_bounds__(NTHR, 2) void gemm8(const hbf* __restrict__ A,
                                                 const hbf* __restrict__ Bt,
                                                 void* __restrict__ Cv,
                                                 const float* __restrict__ bias,
                                                 const void* __restrict__ resv,
                                                 hbf* __restrict__ vtrout,
                                                 int M, int N, int K) {
  constexpr int MR = (BM / WM) / 16, NR = (BN / WN) / 16;
  constexpr int NQ = NR / 2;
  constexpr int RPA = (BM / WM) / 2;
  constexpr int RPB = (BN / WN) / 2;
  constexpr int ASL = (BM / 2) * 64;
  constexpr int BSL = (BN / 2) * 64;
  constexpr int PERBUF = 2 * ASL + 2 * BSL;
  constexpr int ALD = ASL / (8 * NTHR);
  constexpr int BLD = BSL / (8 * NTHR);
  constexpr int LPT = 2 * ALD + 2 * BLD;  // loads per thread per K-tile (=8)
  static_assert(LPT == 8, "vmcnt constant assumes 8 loads/K-tile");

  __shared__ __align__(16) hbf lds[2 * PERBUF];

  const int tid = threadIdx.x;
  const int lane = tid & 63, wave = tid >> 6;
  const int wr = wave / WN, wc = wave % WN;
  const int lr = lane & 15, lg = lane >> 4;

  const int xcd = blockIdx.x & 7, oidx = blockIdx.x >> 3;
  const int gsup = oidx >> 6, r6 = oidx & 63;
  const int m0 = (xcd * 8 + (r6 >> 3)) * BM;
  const int n0 = (gsup * 8 + (r6 & 7)) * BN;

  const hbf* Ab = A + (size_t)m0 * K;
  const hbf* Bb = Bt + (size_t)n0 * K;

  f32x4 acc[MR][NR] = {};

  auto stageA = [&](int mh, int t, int p) {
#pragma unroll
    for (int l = 0; l < ALD; ++l) {
      int ci = l * NTHR + tid;
      int r = ci >> 3, c = ci & 7;
      int piece = r / RPA, rl = r % RPA;
      int grow = piece * (BM / WM) + mh * RPA + rl;
      int gk = t * 64 + ((c ^ (r & 7)) << 3);
      GLDS(Ab + (size_t)grow * K + gk, lds + p * PERBUF + mh * ASL + (size_t)ci * 8);
    }
  };
  auto stageB = [&](int nh, int t, int p) {
#pragma unroll
    for (int l = 0; l < BLD; ++l) {
      int ci = l * NTHR + tid;
      int r = ci >> 3, c = ci & 7;
      int piece = r / RPB, rl = r % RPB;
      int grow = piece * (BN / WN) + nh * RPB + rl;
      int gk = t * 64 + ((c ^ (r & 7)) << 3);
      GLDS(Bb + (size_t)grow * K + gk, lds + p * PERBUF + 2 * ASL + nh * BSL + (size_t)ci * 8);
    }
  };
  auto ldAfull = [&](bf16x8 (&af)[MR][2], int p) {
#pragma unroll
    for (int f = 0; f < MR; ++f)
#pragma unroll
      for (int ks = 0; ks < 2; ++ks) {
        int mh = f >> 1, i = f & 1;
        const hbf* base = lds + p * PERBUF + mh * ASL;
        int row = wr * RPA + i * 16 + lr;
        int slot = (ks * 4 + lg) ^ (lr & 7);
        af[f][ks] = *(const bf16x8*)(base + (size_t)row * 64 + slot * 8);
      }
  };
  auto ldB = [&](bf16x8 (&bf)[NQ][2], int nh, int p) {
    const hbf* base = lds + p * PERBUF + 2 * ASL + nh * BSL;
#pragma unroll
    for (int j = 0; j < NQ; ++j)
#pragma unroll
      for (int ks = 0; ks < 2; ++ks) {
        int row = wc * RPB + j * 16 + lr;
        int slot = (ks * 4 + lg) ^ (lr & 7);
        bf[j][ks] = *(const bf16x8*)(base + (size_t)row * 64 + slot * 8);
      }
  };

#define MFMA_H(av, bv, nh)                                                            \
  do {                                                                                \
    __builtin_amdgcn_s_setprio(1);                                                    \
    _Pragma("unroll") for (int f_ = 0; f_ < MR; ++f_)                                 \
    _Pragma("unroll") for (int j_ = 0; j_ < NQ; ++j_)                                 \
    _Pragma("unroll") for (int k_ = 0; k_ < 2; ++k_)                                  \
      acc[f_][(nh) * NQ + j_] = __builtin_amdgcn_mfma_f32_16x16x32_bf16(              \
          (av)[f_][k_], (bv)[j_][k_], acc[f_][(nh) * NQ + j_], 0, 0, 0);              \
    __builtin_amdgcn_s_setprio(0);                                                    \
  } while (0)

  const int T = K >> 6;

  // prologue: tiles 0,1 fully staged (8+8 loads); keep tile1's 8 in flight
  stageA(0, 0, 0); stageA(1, 0, 0); stageB(0, 0, 0); stageB(1, 0, 0);
  stageA(0, 1, 1); stageA(1, 1, 1); stageB(0, 1, 1); stageB(1, 1, 1);
  s_vmcnt<8>();
  __builtin_amdgcn_s_barrier();

  for (int t = 0; t < T; ++t) {
    const int p = t & 1;
    bf16x8 af[MR][2], b0[NQ][2], b1[NQ][2];
    ldAfull(af, p);
    ldB(b0, 0, p);
    ldB(b1, 1, p);
    asm volatile("s_waitcnt lgkmcnt(0)" ::: "memory");
    __builtin_amdgcn_sched_barrier(0);
    MFMA_H(af, b0, 0);
    MFMA_H(af, b1, 1);
    __builtin_amdgcn_s_barrier();  // all waves done reading buf p
    if (t + 2 < T) {
      stageA(0, t + 2, p); stageA(1, t + 2, p);
      stageB(0, t + 2, p); stageB(1, t + 2, p);
    }
    if (t + 1 < T) {
      if (t + 2 < T) s_vmcnt<8>();  // drain t+1's loads, keep t+2's
      else s_vmcnt<0>();
      __builtin_amdgcn_s_barrier();
    }
  }
#undef MFMA_H

  // ---- epilogue ----
#pragma unroll
  for (int mf = 0; mf < MR; ++mf) {
    int row = m0 + wr * (BM / WM) + mf * 16 + lg * 4;
#pragma unroll
    for (int n = 0; n < NR; ++n) {
      int col = n0 + wc * (BN / WN) + n * 16 + lr;
      float bvl = HAS_BIAS ? bias[col] : 0.f;
      float tv[4];
#pragma unroll
      for (int j = 0; j < 4; ++j) {
        float v = acc[mf][n][j] + bvl;
        if (ACT == 1) v = gelu_f(v);
        if constexpr (RES == 1) v += ((const float*)resv)[(size_t)(row + j) * N + col];
        else if constexpr (RES == 2)
          v += bfu2f(__builtin_bit_cast(unsigned short,
                                        ((const hbf*)resv)[(size_t)(row + j) * N + col]));
        tv[j] = v;
      }
      if constexpr (VTR != 0) {
        if (col >= 2048) {
          ushort4 w;
          w.x = f2bfu(tv[0]); w.y = f2bfu(tv[1]); w.z = f2bfu(tv[2]); w.w = f2bfu(tv[3]);
          int bb = row >> 11;
          size_t vrow = (size_t)(bb * 1024 + col - 2048);
          *(ushort4*)((unsigned short*)vtrout + vrow * Ss + (row & 2047)) = w;
          continue;
        }
      }
#pragma unroll
      for (int j = 0; j < 4; ++j) {
        if (OUT_BF16) ((hbf*)Cv)[(size_t)(row + j) * N + col] = __float2bfloat16(tv[j]);
        else ((float*)Cv)[(size_t)(row + j) * N + col] = tv[j];
      }
    }
  }
}

// ---------------- causal flash attention, swapped QK^T, in-register softmax ---------------
// Grid 1024 = 4 blocks/CU; xcd = gi&7 owns heads {bh: bh&7==xcd}; per-XCD rank orders
// blocks heavy-first ACROSS heads.
__global__ __launch_bounds__(256, 4) void attn_kernel(const hbf* __restrict__ qkv,
                                                      const hbf* __restrict__ vt,
                                                      hbf* __restrict__ ctx) {
  __shared__ __align__(16) hbf Ks[2][64 * 64];
  __shared__ __align__(16) hbf Vs[2][64 * 64];

  const int tid = threadIdx.x;
  const int wave = tid >> 6, lane = tid & 63;
  const int l31 = lane & 31, hi = lane >> 5;

  const int gi = blockIdx.x;
  const int xslot = gi & 7, kk = gi >> 3;
  const int rank = kk >> 3, hg = kk & 7;
  const int bh = hg * 8 + xslot;
  const int bx = 15 - rank;
  const int b = bh >> 4, hh = bh & 15;
  const int q0b = bx * 128;
  const int q0w = q0b + wave * 32;
  const int nsteps = (q0b + 128) >> 6;
  const int my_steps = (q0w + 95) >> 6;

  constexpr float QSCALE = 0.18033688011112042f;  // 0.125 * log2(e)
  bf16x8 qf[4];
  {
    const hbf* qrow = qkv + (size_t)(b * Ss + q0w + l31) * LDQ + hh * 64 + hi * 8;
#pragma unroll
    for (int ds = 0; ds < 4; ++ds) {
      bf16x8 t = *(const bf16x8*)(qrow + ds * 16);
#pragma unroll
      for (int e = 0; e < 8; ++e) qf[ds][e] = (__bf16)((float)t[e] * QSCALE);
    }
  }

  const hbf* kbase = qkv + 1024 + (size_t)(b * Ss) * LDQ + hh * 64;
  const hbf* vbase = vt + (size_t)(bh * 64) * Ss;
  const int i0 = tid, i1 = tid + 256;
  const int r0 = i0 >> 3, s0c = (i0 & 7), r1 = i1 >> 3, s1c = (i1 & 7);
  const int c0 = 8 * (s0c ^ (r0 & 7)), c1 = 8 * (s1c ^ (r1 & 7));

  f32x16 ot[2] = {};
  float m_run = -1e30f, l_run = 0.f;

  {
    hbf* kd = &Ks[0][0];
    hbf* vd = &Vs[0][0];
    GLDS(kbase + (size_t)r0 * LDQ + c0, kd + i0 * 8);
    GLDS(kbase + (size_t)r1 * LDQ + c1, kd + i1 * 8);
    GLDS(vbase + (size_t)r0 * Ss + c0, vd + i0 * 8);
    GLDS(vbase + (size_t)r1 * Ss + c1, vd + i1 * 8);
  }
  __syncthreads();

  int buf = 0;
  for (int it = 0; it < nsteps; ++it) {
    const int k0 = it << 6;
    if (it + 1 < nsteps) {
      hbf* kd = &Ks[buf ^ 1][0];
      hbf* vd = &Vs[buf ^ 1][0];
      GLDS(kbase + (size_t)(k0 + 64 + r0) * LDQ + c0, kd + i0 * 8);
      GLDS(kbase + (size_t)(k0 + 64 + r1) * LDQ + c1, kd + i1 * 8);
      GLDS(vbase + (size_t)r0 * Ss + k0 + 64 + c0, vd + i0 * 8);
      GLDS(vbase + (size_t)r1 * Ss + k0 + 64 + c1, vd + i1 * 8);
    }

    if (it < my_steps) {
      const hbf* kt = &Ks[buf][0];
      f32x16 st[2] = {};
      __builtin_amdgcn_s_setprio(1);
#pragma unroll
      for (int c = 0; c < 2; ++c) {
        const int krow = l31 + 32 * c;
        const int kr7 = krow & 7;
#pragma unroll
        for (int ds = 0; ds < 4; ++ds) {
          bf16x8 kf = *(const bf16x8*)(kt + krow * 64 + 8 * ((ds * 2 + hi) ^ kr7));
          st[c] = __builtin_amdgcn_mfma_f32_32x32x16_bf16(kf, qf[ds], st[c], 0, 0, 0);
        }
      }
      __builtin_amdgcn_s_setprio(0);

      if (it == my_steps - 1) {
        const int qg = q0w + l31;
#pragma unroll
        for (int c = 0; c < 2; ++c)
#pragma unroll
          for (int rg = 0; rg < 16; ++rg) {
            int kg = k0 + c * 32 + (rg & 3) + 8 * (rg >> 2) + 4 * hi;
            if (kg > qg) st[c][rg] = -3e38f;
          }
      }

      float mx = -3e38f;
#pragma unroll
      for (int c = 0; c < 2; ++c)
#pragma unroll
        for (int rg = 0; rg < 16; ++rg) mx = fmaxf(mx, st[c][rg]);
      mx = fmaxf(mx, __shfl_xor(mx, 32));
      if (!__all(mx - m_run <= 11.541560327111707f)) {
        float mn = fmaxf(m_run, mx);
        float sc = exp2f(m_run - mn);
        m_run = mn;
        l_run *= sc;
#pragma unroll
        for (int dc = 0; dc < 2; ++dc)
#pragma unroll
          for (int rg = 0; rg < 16; ++rg) ot[dc][rg] *= sc;
      }
      float rs = 0.f;
#pragma unroll
      for (int c = 0; c < 2; ++c)
#pragma unroll
        for (int rg = 0; rg < 16; ++rg) {
          float p = exp2f(st[c][rg] - m_run);
          st[c][rg] = p;
          rs += p;
        }
      rs += __shfl_xor(rs, 32);
      l_run += rs;

      bf16x8 pf[2][2];
#pragma unroll
      for (int c = 0; c < 2; ++c)
#pragma unroll
        for (int ks = 0; ks < 2; ++ks) {
          const int rb = ks * 8;
          u32 a0 = pkbf(st[c][rb + 0], st[c][rb + 1]);
          u32 a1 = pkbf(st[c][rb + 2], st[c][rb + 3]);
          u32 b0 = pkbf(st[c][rb + 4], st[c][rb + 5]);
          u32 b1 = pkbf(st[c][rb + 6], st[c][rb + 7]);
          u32 pa0 = __shfl_xor(a0, 32), pa1 = __shfl_xor(a1, 32);
          u32 pb0 = __shfl_xor(b0, 32), pb1 = __shfl_xor(b1, 32);
          u32x4 f;
          f.x = hi ? pb0 : a0;
          f.y = hi ? pb1 : a1;
          f.z = hi ? b0 : pa0;
          f.w = hi ? b1 : pa1;
          pf[c][ks] = __builtin_bit_cast(bf16x8, f);
        }

      const hbf* vtl = &Vs[buf][0];
      __builtin_amdgcn_s_setprio(1);
#pragma unroll
      for (int dc = 0; dc < 2; ++dc) {
        const int vrow = l31 + 32 * dc;
        const int vr7 = vrow & 7;
#pragma unroll
        for (int c = 0; c < 2; ++c)
#pragma unroll
          for (int ks = 0; ks < 2; ++ks) {
            bf16x8 vf = *(const bf16x8*)(vtl + vrow * 64 + 8 * ((c * 4 + ks * 2 + hi) ^ vr7));
            ot[dc] = __builtin_amdgcn_mfma_f32_32x32x16_bf16(vf, pf[c][ks], ot[dc], 0, 0, 0);
          }
      }
      __builtin_amdgcn_s_setprio(0);
    }

    __syncthreads();
    buf ^= 1;
  }

  const float inv = __builtin_amdgcn_rcpf(l_run);
  hbf* crow = ctx + (size_t)(b * Ss + q0w + l31) * Dm + hh * 64;
#pragma unroll
  for (int dc = 0; dc < 2; ++dc)
#pragma unroll
    for (int rg = 0; rg < 4; ++rg) {
      ushort4 w;
      w.x = f2bfu(ot[dc][rg * 4 + 0] * inv);
      w.y = f2bfu(ot[dc][rg * 4 + 1] * inv);
      w.z = f2bfu(ot[dc][rg * 4 + 2] * inv);
      w.w = f2bfu(ot[dc][rg * 4 + 3] * inv);
      *(ushort4*)(crow + dc * 32 + rg * 8 + hi * 4) = w;
    }
}

// -----------------------------------------------------------------------------------------
extern "C" void kernel_launch(void* const* d_in, const int* in_sizes, int n_in,
                              void* d_out, int out_size, void* d_ws, size_t ws_size,
                              hipStream_t stream) {
  const float* x  = (const float*)d_in[0];
  const float* Wq = (const float*)d_in[1];
  const float* Wk = (const float*)d_in[2];
  const float* Wv = (const float*)d_in[3];
  const float* Wo = (const float*)d_in[4];
  const float* bo = (const float*)d_in[5];
  const float* W1 = (const float*)d_in[6];
  const float* b1 = (const float*)d_in[7];
  const float* W2 = (const float*)d_in[8];
  const float* b2 = (const float*)d_in[9];
  const float* g1 = (const float*)d_in[10];
  const float* s1 = (const float*)d_in[11];
  const float* g2 = (const float*)d_in[12];
  const float* s2 = (const float*)d_in[13];
  float* out = (float*)d_out;

  char* ws = (char*)d_ws;
  constexpr size_t MB = 1024ull * 1024ull;
  hbf* wqkvT = (hbf*)(ws + 0 * MB);    // 6MB [3072][1024]
  hbf* woT   = (hbf*)(ws + 6 * MB);    // 2MB
  hbf* w1T   = (hbf*)(ws + 8 * MB);    // 8MB
  hbf* w2T   = (hbf*)(ws + 16 * MB);   // 8MB
  hbf* xln   = (hbf*)(ws + 24 * MB);   // 16MB (reused: ctx, then y2)
  hbf* ctx   = (hbf*)(ws + 24 * MB);
  hbf* y2    = (hbf*)(ws + 24 * MB);
  hbf* qkvb  = (hbf*)(ws + 40 * MB);   // 48MB [8192][3072] (V range unused)
  hbf* vtb   = (hbf*)(ws + 88 * MB);   // 16MB
  hbf* ff1   = (hbf*)(ws + 40 * MB);   // 64MB (over dead qkv/vt)
  hbf* hbb   = (hbf*)(ws + 104 * MB);  // 16MB bf16 residual trunk
  (void)ws_size; (void)in_sizes; (void)n_in; (void)out_size;

  const int BS = Bb * Ss;  // 8192 rows

  // 1) weights->bf16 transposed + LN1, one fused launch
  prep_kernel<<<20480, 256, 0, stream>>>(Wq, Wk, Wv, Wo, W1, W2,
                                         wqkvT, woT, w1T, w2T, x, g1, s1, xln);

  // 2) fused QKV projection; V panels written transposed to vtb
  gemm8<128, 128, 2, 2, 256, 0, false, 0, true, 1><<<1536, 256, 0, stream>>>(
      xln, wqkvT, qkvb, nullptr, nullptr, vtb, BS, LDQ, Dm);

  // 3) flash attention
  attn_kernel<<<dim3(1024), 256, 0, stream>>>(qkvb, vtb, ctx);

  // 4) output projection + bias + residual(x fp32) -> h (bf16)
  gemm8<128, 128, 2, 2, 256, 0, true, 1, true, 0><<<512, 256, 0, stream>>>(
      ctx, woT, hbb, bo, x, nullptr, BS, Dm, Dm);

  // 5) LN2 (bf16 in)
  ln_kernel<<<BS, 256, 0, stream>>>(hbb, g2, s2, y2);

  // 6) FF1 + bias + GELU
  gemm8<128, 128, 2, 2, 256, 1, true, 0, true, 0><<<2048, 256, 0, stream>>>(
      y2, w1T, ff1, b1, nullptr, nullptr, BS, DFm, Dm);

  // 7) FF2 + bias + residual(h bf16) -> out (fp32)
  gemm8<128, 128, 2, 2, 256, 0, true, 2, false, 0><<<512, 256, 0, stream>>>(
      ff1, w2T, out, b2, hbb, nullptr, BS, Dm, DFm);
}

// Round 18
// 323.495 us; speedup vs baseline: 1.0413x; 1.0413x over previous
//
#include <hip/hip_runtime.h>
#include <hip/hip_bf16.h>

#define DEV __device__ __forceinline__

typedef __bf16 bf16x8 __attribute__((ext_vector_type(8)));
typedef __bf16 bf16x2v __attribute__((ext_vector_type(2)));
typedef float f32x4 __attribute__((ext_vector_type(4)));
typedef float f32x16 __attribute__((ext_vector_type(16)));
typedef unsigned int u32;
typedef unsigned int u32x4 __attribute__((ext_vector_type(4)));
typedef __hip_bfloat16 hbf;

constexpr int Dm = 1024;
constexpr int Hh = 16;
constexpr int Ss = 2048;
constexpr int Bb = 4;
constexpr int DFm = 4096;
constexpr int LDQ = 3072;  // fused qkv row stride

DEV unsigned short f2bfu(float f) {
  hbf h = __float2bfloat16(f);
  return __builtin_bit_cast(unsigned short, h);
}

DEV float bfu2f(unsigned short u) { return __builtin_bit_cast(float, (u32)u << 16); }

DEV u32 pkbf(float x, float y) {
  bf16x2v v = {(__bf16)x, (__bf16)y};
  return __builtin_bit_cast(u32, v);
}

// raw v_exp_f32 (1 instr). Safe: args <= 0 here; -3e38 -> 0 exactly.
DEV float fexp2(float x) { return __builtin_amdgcn_exp2f(x); }

DEV float gelu_f(float x) {
  float e = __expf(-1.5957691216057308f * (x + 0.044715f * x * x * x));
  return x * __builtin_amdgcn_rcpf(1.f + e);
}

template <int N>
DEV void s_vmcnt() {
  if constexpr (N == 0) asm volatile("s_waitcnt vmcnt(0)" ::: "memory");
  else if constexpr (N == 5) asm volatile("s_waitcnt vmcnt(5)" ::: "memory");
  else if constexpr (N == 6) asm volatile("s_waitcnt vmcnt(6)" ::: "memory");
  else if constexpr (N == 8) asm volatile("s_waitcnt vmcnt(8)" ::: "memory");
  else static_assert(N == 0, "unsupported vmcnt");
}

#define GLDS(src, dst)                                                                     \
  __builtin_amdgcn_global_load_lds((const __attribute__((address_space(1))) void*)(src),   \
                                   (__attribute__((address_space(3))) void*)(dst), 16, 0, 0)

// ========== fused prep: 6 weight transposes (blocks 0..12287) + LN1 (blocks 12288..20479) =
__global__ __launch_bounds__(256) void prep_kernel(
    const float* __restrict__ Wq, const float* __restrict__ Wk,
    const float* __restrict__ Wv, const float* __restrict__ Wo,
    const float* __restrict__ W1, const float* __restrict__ W2,
    hbf* __restrict__ dqkv, hbf* __restrict__ dwo,
    hbf* __restrict__ dw1, hbf* __restrict__ dw2,
    const float* __restrict__ x, const float* __restrict__ g1,
    const float* __restrict__ s1, hbf* __restrict__ xln) {
  const int i = blockIdx.x;
  if (i < 12288) {
    __shared__ float tile[32][33];
    const float* W;
    hbf* Wt;
    int K, N, k0, n0;
    if (i < 4096) {
      int z = i >> 10, j = i & 1023;
      W = z == 0 ? Wq : z == 1 ? Wk : z == 2 ? Wv : Wo;
      Wt = z == 3 ? dwo : dqkv + (size_t)z * 1024 * 1024;
      K = 1024; N = 1024; k0 = (j & 31) * 32; n0 = (j >> 5) * 32;
    } else if (i < 8192) {
      int j = i - 4096;
      W = W1; Wt = dw1; K = 1024; N = 4096;
      k0 = (j & 31) * 32; n0 = (j >> 5) * 32;
    } else {
      int j = i - 8192;
      W = W2; Wt = dw2; K = 4096; N = 1024;
      k0 = (j & 127) * 32; n0 = (j >> 7) * 32;
    }
    int tx = threadIdx.x & 31, ty = threadIdx.x >> 5;
    for (int r = ty; r < 32; r += 8) tile[r][tx] = W[(size_t)(k0 + r) * N + n0 + tx];
    __syncthreads();
    for (int r = ty; r < 32; r += 8)
      Wt[(size_t)(n0 + r) * K + k0 + tx] = __float2bfloat16(tile[tx][r]);
  } else {
    const int bid = i - 12288;
    int row = ((bid & 7) << 10) | (bid >> 3);  // row->XCD remap
    int t = threadIdx.x;
    float4 v = ((const float4*)(x + (size_t)row * Dm))[t];
    float s = v.x + v.y + v.z + v.w;
    float q = v.x * v.x + v.y * v.y + v.z * v.z + v.w * v.w;
#pragma unroll
    for (int off = 32; off > 0; off >>= 1) {
      s += __shfl_down(s, off);
      q += __shfl_down(q, off);
    }
    __shared__ float red[10];
    int wave = t >> 6, lane = t & 63;
    if (lane == 0) { red[wave] = s; red[4 + wave] = q; }
    __syncthreads();
    if (t == 0) {
      float ts = red[0] + red[1] + red[2] + red[3];
      float tq = red[4] + red[5] + red[6] + red[7];
      float mean = ts * (1.f / Dm);
      float var = tq * (1.f / Dm) - mean * mean;
      red[8] = mean;
      red[9] = rsqrtf(var + 1e-5f);
    }
    __syncthreads();
    float mean = red[8], inv = red[9];
    float4 gv = ((const float4*)g1)[t];
    float4 bv = ((const float4*)s1)[t];
    ushort4 o;
    o.x = f2bfu(gv.x * (v.x - mean) * inv + bv.x);
    o.y = f2bfu(gv.y * (v.y - mean) * inv + bv.y);
    o.z = f2bfu(gv.z * (v.z - mean) * inv + bv.z);
    o.w = f2bfu(gv.w * (v.w - mean) * inv + bv.w);
    ((ushort4*)(xln + (size_t)row * Dm))[t] = o;
  }
}

// ---------------- layernorm (bf16 in, bf16 out), one block per row, row->XCD remap --------
__global__ __launch_bounds__(256) void ln_kernel(const hbf* __restrict__ xv,
                                                 const float* __restrict__ g,
                                                 const float* __restrict__ b,
                                                 hbf* __restrict__ y) {
  int row = ((blockIdx.x & 7) << 10) | (blockIdx.x >> 3);
  int t = threadIdx.x;
  float4 v;
  ushort4 u = ((const ushort4*)(xv + (size_t)row * Dm))[t];
  v.x = bfu2f(u.x); v.y = bfu2f(u.y); v.z = bfu2f(u.z); v.w = bfu2f(u.w);
  float s = v.x + v.y + v.z + v.w;
  float q = v.x * v.x + v.y * v.y + v.z * v.z + v.w * v.w;
#pragma unroll
  for (int off = 32; off > 0; off >>= 1) {
    s += __shfl_down(s, off);
    q += __shfl_down(q, off);
  }
  __shared__ float red[10];
  int wave = t >> 6, lane = t & 63;
  if (lane == 0) { red[wave] = s; red[4 + wave] = q; }
  __syncthreads();
  if (t == 0) {
    float ts = red[0] + red[1] + red[2] + red[3];
    float tq = red[4] + red[5] + red[6] + red[7];
    float mean = ts * (1.f / Dm);
    float var = tq * (1.f / Dm) - mean * mean;
    red[8] = mean;
    red[9] = rsqrtf(var + 1e-5f);
  }
  __syncthreads();
  float mean = red[8], inv = red[9];
  float4 gv = ((const float4*)g)[t];
  float4 bv = ((const float4*)b)[t];
  ushort4 o;
  o.x = f2bfu(gv.x * (v.x - mean) * inv + bv.x);
  o.y = f2bfu(gv.y * (v.y - mean) * inv + bv.y);
  o.z = f2bfu(gv.z * (v.z - mean) * inv + bv.z);
  o.w = f2bfu(gv.w * (v.w - mean) * inv + bv.w);
  ((ushort4*)(y + (size_t)row * Dm))[t] = o;
}

// ================= tiled GEMM, single-phase K-loop, 2 blocks/CU, L2-supertiled ============
// (unchanged from R17 — see its header comment)
template <int BM, int BN, int WM, int WN, int NTHR, int ACT, bool HAS_BIAS, int RES,
          bool OUT_BF16, int VTR>
__global__ __launch_bounds__(NTHR, 2) void gemm8(const hbf* __restrict__ A,
                                                 const hbf* __restrict__ Bt,
                                                 void* __restrict__ Cv,
                                                 const float* __restrict__ bias,
                                                 const void* __restrict__ resv,
                                                 hbf* __restrict__ vtrout,
                                                 int M, int N, int K) {
  constexpr int MR = (BM / WM) / 16, NR = (BN / WN) / 16;
  constexpr int NQ = NR / 2;
  constexpr int RPA = (BM / WM) / 2;
  constexpr int RPB = (BN / WN) / 2;
  constexpr int ASL = (BM / 2) * 64;
  constexpr int BSL = (BN / 2) * 64;
  constexpr int PERBUF = 2 * ASL + 2 * BSL;
  constexpr int ALD = ASL / (8 * NTHR);
  constexpr int BLD = BSL / (8 * NTHR);
  constexpr int LPT = 2 * ALD + 2 * BLD;
  static_assert(LPT == 8, "vmcnt constant assumes 8 loads/K-tile");

  __shared__ __align__(16) hbf lds[2 * PERBUF];

  const int tid = threadIdx.x;
  const int lane = tid & 63, wave = tid >> 6;
  const int wr = wave / WN, wc = wave % WN;
  const int lr = lane & 15, lg = lane >> 4;

  const int xcd = blockIdx.x & 7, oidx = blockIdx.x >> 3;
  const int gsup = oidx >> 6, r6 = oidx & 63;
  const int m0 = (xcd * 8 + (r6 >> 3)) * BM;
  const int n0 = (gsup * 8 + (r6 & 7)) * BN;

  const hbf* Ab = A + (size_t)m0 * K;
  const hbf* Bb = Bt + (size_t)n0 * K;

  f32x4 acc[MR][NR] = {};

  auto stageA = [&](int mh, int t, int p) {
#pragma unroll
    for (int l = 0; l < ALD; ++l) {
      int ci = l * NTHR + tid;
      int r = ci >> 3, c = ci & 7;
      int piece = r / RPA, rl = r % RPA;
      int grow = piece * (BM / WM) + mh * RPA + rl;
      int gk = t * 64 + ((c ^ (r & 7)) << 3);
      GLDS(Ab + (size_t)grow * K + gk, lds + p * PERBUF + mh * ASL + (size_t)ci * 8);
    }
  };
  auto stageB = [&](int nh, int t, int p) {
#pragma unroll
    for (int l = 0; l < BLD; ++l) {
      int ci = l * NTHR + tid;
      int r = ci >> 3, c = ci & 7;
      int piece = r / RPB, rl = r % RPB;
      int grow = piece * (BN / WN) + nh * RPB + rl;
      int gk = t * 64 + ((c ^ (r & 7)) << 3);
      GLDS(Bb + (size_t)grow * K + gk, lds + p * PERBUF + 2 * ASL + nh * BSL + (size_t)ci * 8);
    }
  };
  auto ldAfull = [&](bf16x8 (&af)[MR][2], int p) {
#pragma unroll
    for (int f = 0; f < MR; ++f)
#pragma unroll
      for (int ks = 0; ks < 2; ++ks) {
        int mh = f >> 1, i = f & 1;
        const hbf* base = lds + p * PERBUF + mh * ASL;
        int row = wr * RPA + i * 16 + lr;
        int slot = (ks * 4 + lg) ^ (lr & 7);
        af[f][ks] = *(const bf16x8*)(base + (size_t)row * 64 + slot * 8);
      }
  };
  auto ldB = [&](bf16x8 (&bf)[NQ][2], int nh, int p) {
    const hbf* base = lds + p * PERBUF + 2 * ASL + nh * BSL;
#pragma unroll
    for (int j = 0; j < NQ; ++j)
#pragma unroll
      for (int ks = 0; ks < 2; ++ks) {
        int row = wc * RPB + j * 16 + lr;
        int slot = (ks * 4 + lg) ^ (lr & 7);
        bf[j][ks] = *(const bf16x8*)(base + (size_t)row * 64 + slot * 8);
      }
  };

#define MFMA_H(av, bv, nh)                                                            \
  do {                                                                                \
    __builtin_amdgcn_s_setprio(1);                                                    \
    _Pragma("unroll") for (int f_ = 0; f_ < MR; ++f_)                                 \
    _Pragma("unroll") for (int j_ = 0; j_ < NQ; ++j_)                                 \
    _Pragma("unroll") for (int k_ = 0; k_ < 2; ++k_)                                  \
      acc[f_][(nh) * NQ + j_] = __builtin_amdgcn_mfma_f32_16x16x32_bf16(              \
          (av)[f_][k_], (bv)[j_][k_], acc[f_][(nh) * NQ + j_], 0, 0, 0);              \
    __builtin_amdgcn_s_setprio(0);                                                    \
  } while (0)

  const int T = K >> 6;

  stageA(0, 0, 0); stageA(1, 0, 0); stageB(0, 0, 0); stageB(1, 0, 0);
  stageA(0, 1, 1); stageA(1, 1, 1); stageB(0, 1, 1); stageB(1, 1, 1);
  s_vmcnt<8>();
  __builtin_amdgcn_s_barrier();

  for (int t = 0; t < T; ++t) {
    const int p = t & 1;
    bf16x8 af[MR][2], b0[NQ][2], b1[NQ][2];
    ldAfull(af, p);
    ldB(b0, 0, p);
    ldB(b1, 1, p);
    asm volatile("s_waitcnt lgkmcnt(0)" ::: "memory");
    __builtin_amdgcn_sched_barrier(0);
    MFMA_H(af, b0, 0);
    MFMA_H(af, b1, 1);
    __builtin_amdgcn_s_barrier();
    if (t + 2 < T) {
      stageA(0, t + 2, p); stageA(1, t + 2, p);
      stageB(0, t + 2, p); stageB(1, t + 2, p);
    }
    if (t + 1 < T) {
      if (t + 2 < T) s_vmcnt<8>();
      else s_vmcnt<0>();
      __builtin_amdgcn_s_barrier();
    }
  }
#undef MFMA_H

#pragma unroll
  for (int mf = 0; mf < MR; ++mf) {
    int row = m0 + wr * (BM / WM) + mf * 16 + lg * 4;
#pragma unroll
    for (int n = 0; n < NR; ++n) {
      int col = n0 + wc * (BN / WN) + n * 16 + lr;
      float bvl = HAS_BIAS ? bias[col] : 0.f;
      float tv[4];
#pragma unroll
      for (int j = 0; j < 4; ++j) {
        float v = acc[mf][n][j] + bvl;
        if (ACT == 1) v = gelu_f(v);
        if constexpr (RES == 1) v += ((const float*)resv)[(size_t)(row + j) * N + col];
        else if constexpr (RES == 2)
          v += bfu2f(__builtin_bit_cast(unsigned short,
                                        ((const hbf*)resv)[(size_t)(row + j) * N + col]));
        tv[j] = v;
      }
      if constexpr (VTR != 0) {
        if (col >= 2048) {
          ushort4 w;
          w.x = f2bfu(tv[0]); w.y = f2bfu(tv[1]); w.z = f2bfu(tv[2]); w.w = f2bfu(tv[3]);
          int bb = row >> 11;
          size_t vrow = (size_t)(bb * 1024 + col - 2048);
          *(ushort4*)((unsigned short*)vtrout + vrow * Ss + (row & 2047)) = w;
          continue;
        }
      }
#pragma unroll
      for (int j = 0; j < 4; ++j) {
        if (OUT_BF16) ((hbf*)Cv)[(size_t)(row + j) * N + col] = __float2bfloat16(tv[j]);
        else ((float*)Cv)[(size_t)(row + j) * N + col] = tv[j];
      }
    }
  }
}

// ---------------- causal flash attention, swapped QK^T, in-register softmax ---------------
// Grid 1024 = 4 blocks/CU; xcd = gi&7 owns heads {bh: bh&7==xcd}; per-XCD rank heavy-first.
// R18: raw v_exp_f32 (fexp2) for softmax; incremental K/V staging pointers (+= per step).
__global__ __launch_bounds__(256, 4) void attn_kernel(const hbf* __restrict__ qkv,
                                                      const hbf* __restrict__ vt,
                                                      hbf* __restrict__ ctx) {
  __shared__ __align__(16) hbf Ks[2][64 * 64];
  __shared__ __align__(16) hbf Vs[2][64 * 64];

  const int tid = threadIdx.x;
  const int wave = tid >> 6, lane = tid & 63;
  const int l31 = lane & 31, hi = lane >> 5;

  const int gi = blockIdx.x;
  const int xslot = gi & 7, kk = gi >> 3;
  const int rank = kk >> 3, hg = kk & 7;
  const int bh = hg * 8 + xslot;
  const int bx = 15 - rank;
  const int b = bh >> 4, hh = bh & 15;
  const int q0b = bx * 128;
  const int q0w = q0b + wave * 32;
  const int nsteps = (q0b + 128) >> 6;
  const int my_steps = (q0w + 95) >> 6;

  constexpr float QSCALE = 0.18033688011112042f;  // 0.125 * log2(e)
  bf16x8 qf[4];
  {
    const hbf* qrow = qkv + (size_t)(b * Ss + q0w + l31) * LDQ + hh * 64 + hi * 8;
#pragma unroll
    for (int ds = 0; ds < 4; ++ds) {
      bf16x8 t = *(const bf16x8*)(qrow + ds * 16);
#pragma unroll
      for (int e = 0; e < 8; ++e) qf[ds][e] = (__bf16)((float)t[e] * QSCALE);
    }
  }

  const int i0 = tid, i1 = tid + 256;
  const int r0 = i0 >> 3, s0c = (i0 & 7), r1 = i1 >> 3, s1c = (i1 & 7);
  const int c0 = 8 * (s0c ^ (r0 & 7)), c1 = 8 * (s1c ^ (r1 & 7));

  // incremental staging pointers (advance per step: K by 64*LDQ, V by 64)
  const hbf* kbase = qkv + 1024 + (size_t)(b * Ss) * LDQ + hh * 64;
  const hbf* vbase = vt + (size_t)(bh * 64) * Ss;
  const hbf* kp0 = kbase + (size_t)r0 * LDQ + c0;
  const hbf* kp1 = kbase + (size_t)r1 * LDQ + c1;
  const hbf* vp0 = vbase + (size_t)r0 * Ss + c0;
  const hbf* vp1 = vbase + (size_t)r1 * Ss + c1;

  f32x16 ot[2] = {};
  float m_run = -1e30f, l_run = 0.f;

  {
    GLDS(kp0, &Ks[0][0] + i0 * 8);
    GLDS(kp1, &Ks[0][0] + i1 * 8);
    GLDS(vp0, &Vs[0][0] + i0 * 8);
    GLDS(vp1, &Vs[0][0] + i1 * 8);
    kp0 += (size_t)64 * LDQ; kp1 += (size_t)64 * LDQ;
    vp0 += 64; vp1 += 64;
  }
  __syncthreads();

  int buf = 0;
  for (int it = 0; it < nsteps; ++it) {
    const int k0 = it << 6;
    if (it + 1 < nsteps) {
      hbf* kd = &Ks[buf ^ 1][0];
      hbf* vd = &Vs[buf ^ 1][0];
      GLDS(kp0, kd + i0 * 8);
      GLDS(kp1, kd + i1 * 8);
      GLDS(vp0, vd + i0 * 8);
      GLDS(vp1, vd + i1 * 8);
      kp0 += (size_t)64 * LDQ; kp1 += (size_t)64 * LDQ;
      vp0 += 64; vp1 += 64;
    }

    if (it < my_steps) {
      const hbf* kt = &Ks[buf][0];
      f32x16 st[2] = {};
      __builtin_amdgcn_s_setprio(1);
#pragma unroll
      for (int c = 0; c < 2; ++c) {
        const int krow = l31 + 32 * c;
        const int kr7 = krow & 7;
#pragma unroll
        for (int ds = 0; ds < 4; ++ds) {
          bf16x8 kf = *(const bf16x8*)(kt + krow * 64 + 8 * ((ds * 2 + hi) ^ kr7));
          st[c] = __builtin_amdgcn_mfma_f32_32x32x16_bf16(kf, qf[ds], st[c], 0, 0, 0);
        }
      }
      __builtin_amdgcn_s_setprio(0);

      if (it == my_steps - 1) {
        const int qg = q0w + l31;
#pragma unroll
        for (int c = 0; c < 2; ++c)
#pragma unroll
          for (int rg = 0; rg < 16; ++rg) {
            int kg = k0 + c * 32 + (rg & 3) + 8 * (rg >> 2) + 4 * hi;
            if (kg > qg) st[c][rg] = -3e38f;
          }
      }

      float mx = -3e38f;
#pragma unroll
      for (int c = 0; c < 2; ++c)
#pragma unroll
        for (int rg = 0; rg < 16; ++rg) mx = fmaxf(mx, st[c][rg]);
      mx = fmaxf(mx, __shfl_xor(mx, 32));
      if (!__all(mx - m_run <= 11.541560327111707f)) {
        float mn = fmaxf(m_run, mx);
        float sc = fexp2(m_run - mn);
        m_run = mn;
        l_run *= sc;
#pragma unroll
        for (int dc = 0; dc < 2; ++dc)
#pragma unroll
          for (int rg = 0; rg < 16; ++rg) ot[dc][rg] *= sc;
      }
      float rs = 0.f;
#pragma unroll
      for (int c = 0; c < 2; ++c)
#pragma unroll
        for (int rg = 0; rg < 16; ++rg) {
          float p = fexp2(st[c][rg] - m_run);
          st[c][rg] = p;
          rs += p;
        }
      rs += __shfl_xor(rs, 32);
      l_run += rs;

      bf16x8 pf[2][2];
#pragma unroll
      for (int c = 0; c < 2; ++c)
#pragma unroll
        for (int ks = 0; ks < 2; ++ks) {
          const int rb = ks * 8;
          u32 a0 = pkbf(st[c][rb + 0], st[c][rb + 1]);
          u32 a1 = pkbf(st[c][rb + 2], st[c][rb + 3]);
          u32 b0 = pkbf(st[c][rb + 4], st[c][rb + 5]);
          u32 b1 = pkbf(st[c][rb + 6], st[c][rb + 7]);
          u32 pa0 = __shfl_xor(a0, 32), pa1 = __shfl_xor(a1, 32);
          u32 pb0 = __shfl_xor(b0, 32), pb1 = __shfl_xor(b1, 32);
          u32x4 f;
          f.x = hi ? pb0 : a0;
          f.y = hi ? pb1 : a1;
          f.z = hi ? b0 : pa0;
          f.w = hi ? b1 : pa1;
          pf[c][ks] = __builtin_bit_cast(bf16x8, f);
        }

      const hbf* vtl = &Vs[buf][0];
      __builtin_amdgcn_s_setprio(1);
#pragma unroll
      for (int dc = 0; dc < 2; ++dc) {
        const int vrow = l31 + 32 * dc;
        const int vr7 = vrow & 7;
#pragma unroll
        for (int c = 0; c < 2; ++c)
#pragma unroll
          for (int ks = 0; ks < 2; ++ks) {
            bf16x8 vf = *(const bf16x8*)(vtl + vrow * 64 + 8 * ((c * 4 + ks * 2 + hi) ^ vr7));
            ot[dc] = __builtin_amdgcn_mfma_f32_32x32x16_bf16(vf, pf[c][ks], ot[dc], 0, 0, 0);
          }
      }
      __builtin_amdgcn_s_setprio(0);
    }

    __syncthreads();
    buf ^= 1;
  }

  const float inv = __builtin_amdgcn_rcpf(l_run);
  hbf* crow = ctx + (size_t)(b * Ss + q0w + l31) * Dm + hh * 64;
#pragma unroll
  for (int dc = 0; dc < 2; ++dc)
#pragma unroll
    for (int rg = 0; rg < 4; ++rg) {
      ushort4 w;
      w.x = f2bfu(ot[dc][rg * 4 + 0] * inv);
      w.y = f2bfu(ot[dc][rg * 4 + 1] * inv);
      w.z = f2bfu(ot[dc][rg * 4 + 2] * inv);
      w.w = f2bfu(ot[dc][rg * 4 + 3] * inv);
      *(ushort4*)(crow + dc * 32 + rg * 8 + hi * 4) = w;
    }
}

// -----------------------------------------------------------------------------------------
extern "C" void kernel_launch(void* const* d_in, const int* in_sizes, int n_in,
                              void* d_out, int out_size, void* d_ws, size_t ws_size,
                              hipStream_t stream) {
  const float* x  = (const float*)d_in[0];
  const float* Wq = (const float*)d_in[1];
  const float* Wk = (const float*)d_in[2];
  const float* Wv = (const float*)d_in[3];
  const float* Wo = (const float*)d_in[4];
  const float* bo = (const float*)d_in[5];
  const float* W1 = (const float*)d_in[6];
  const float* b1 = (const float*)d_in[7];
  const float* W2 = (const float*)d_in[8];
  const float* b2 = (const float*)d_in[9];
  const float* g1 = (const float*)d_in[10];
  const float* s1 = (const float*)d_in[11];
  const float* g2 = (const float*)d_in[12];
  const float* s2 = (const float*)d_in[13];
  float* out = (float*)d_out;

  char* ws = (char*)d_ws;
  constexpr size_t MB = 1024ull * 1024ull;
  hbf* wqkvT = (hbf*)(ws + 0 * MB);    // 6MB [3072][1024]
  hbf* woT   = (hbf*)(ws + 6 * MB);    // 2MB
  hbf* w1T   = (hbf*)(ws + 8 * MB);    // 8MB
  hbf* w2T   = (hbf*)(ws + 16 * MB);   // 8MB
  hbf* xln   = (hbf*)(ws + 24 * MB);   // 16MB (reused: ctx, then y2)
  hbf* ctx   = (hbf*)(ws + 24 * MB);
  hbf* y2    = (hbf*)(ws + 24 * MB);
  hbf* qkvb  = (hbf*)(ws + 40 * MB);   // 48MB [8192][3072] (V range unused)
  hbf* vtb   = (hbf*)(ws + 88 * MB);   // 16MB
  hbf* ff1   = (hbf*)(ws + 40 * MB);   // 64MB (over dead qkv/vt)
  hbf* hbb   = (hbf*)(ws + 104 * MB);  // 16MB bf16 residual trunk
  (void)ws_size; (void)in_sizes; (void)n_in; (void)out_size;

  const int BS = Bb * Ss;  // 8192 rows

  // 1) weights->bf16 transposed + LN1, one fused launch
  prep_kernel<<<20480, 256, 0, stream>>>(Wq, Wk, Wv, Wo, W1, W2,
                                         wqkvT, woT, w1T, w2T, x, g1, s1, xln);

  // 2) fused QKV projection; V panels written transposed to vtb
  gemm8<128, 128, 2, 2, 256, 0, false, 0, true, 1><<<1536, 256, 0, stream>>>(
      xln, wqkvT, qkvb, nullptr, nullptr, vtb, BS, LDQ, Dm);

  // 3) flash attention
  attn_kernel<<<dim3(1024), 256, 0, stream>>>(qkvb, vtb, ctx);

  // 4) output projection + bias + residual(x fp32) -> h (bf16)
  gemm8<128, 128, 2, 2, 256, 0, true, 1, true, 0><<<512, 256, 0, stream>>>(
      ctx, woT, hbb, bo, x, nullptr, BS, Dm, Dm);

  // 5) LN2 (bf16 in)
  ln_kernel<<<BS, 256, 0, stream>>>(hbb, g2, s2, y2);

  // 6) FF1 + bias + GELU
  gemm8<128, 128, 2, 2, 256, 1, true, 0, true, 0><<<2048, 256, 0, stream>>>(
      y2, w1T, ff1, b1, nullptr, nullptr, BS, DFm, Dm);

  // 7) FF2 + bias + residual(h bf16) -> out (fp32)
  gemm8<128, 128, 2, 2, 256, 0, true, 2, false, 0><<<512, 256, 0, stream>>>(
      ff1, w2T, out, b2, hbb, nullptr, BS, Dm, DFm);
}